// Round 10
// baseline (604.824 us; speedup 1.0000x reference)
//
#include <hip/hip_runtime.h>
#include <hip/hip_bf16.h>
#include <stdint.h>

#define HIDDEN  1024
#define FFN_DIM 2048
#define NEXP    8
#define NTOK    2048          // B*S
#define MAXROWS 5120          // sum of 64-padded per-expert counts <= 4096 + 8*63

typedef short bf16x8 __attribute__((ext_vector_type(8)));
typedef float f32x4  __attribute__((ext_vector_type(4)));

// ---------------- ws layout (bytes) ----------------
static const size_t OFF_CNT  = 0;                         // 8 ints
static const size_t OFF_BASE = 64;                        // 9 ints
static const size_t OFF_TOK  = 128;                       // 8*2048 ints
static const size_t OFF_WGT  = OFF_TOK + (size_t)NEXP*NTOK*4;
static const size_t OFF_XBF  = 131328;                    // 256-aligned
static const size_t XBF_B    = (size_t)NTOK*HIDDEN*2;
static const size_t OFF_H    = OFF_XBF + XBF_B;
static const size_t H_B      = (size_t)MAXROWS*FFN_DIM*2;
static const size_t WS_NEED  = OFF_H + H_B;               // ~25 MB

__device__ __forceinline__ unsigned short f2bf(float f) {
  union { float f; unsigned u; } a; a.f = f;
  unsigned r = a.u + 0x7fff + ((a.u >> 16) & 1);          // RTN-even
  return (unsigned short)(r >> 16);
}

// 8 fp32 -> bf16x8 via packed cvt (memory order preserved)
__device__ __forceinline__ bf16x8 cvt8b(float4 a, float4 b) {
  union { uint4 u; bf16x8 v; } r;
  asm("v_cvt_pk_bf16_f32 %0, %1, %2" : "=v"(r.u.x) : "v"(a.x), "v"(a.y));
  asm("v_cvt_pk_bf16_f32 %0, %1, %2" : "=v"(r.u.y) : "v"(a.z), "v"(a.w));
  asm("v_cvt_pk_bf16_f32 %0, %1, %2" : "=v"(r.u.z) : "v"(b.x), "v"(b.y));
  asm("v_cvt_pk_bf16_f32 %0, %1, %2" : "=v"(r.u.w) : "v"(b.z), "v"(b.w));
  return r.v;
}

__device__ __forceinline__ void ld_g2l16(const void* gsrc, void* ldst) {
  __builtin_amdgcn_global_load_lds(
      (const __attribute__((address_space(1))) unsigned int*)gsrc,
      (__attribute__((address_space(3))) unsigned int*)ldst, 16, 0, 0);
}

// ---------------- Router: fp32-exact logits, top-2, renorm weights, bins; fused x->bf16 --------
__global__ __launch_bounds__(256) void router_kernel(
    const float* __restrict__ x, const float* __restrict__ gw,
    float* __restrict__ logits, int* __restrict__ cnt,
    int* __restrict__ tok, float* __restrict__ wgt,
    unsigned short* __restrict__ xbf)
{
  const int t   = blockIdx.x;
  const int tid = threadIdx.x;
  float4 xv = ((const float4*)(x + (size_t)t * HIDDEN))[tid];
  if (xbf) {
    ushort4 o;
    o.x = f2bf(xv.x); o.y = f2bf(xv.y); o.z = f2bf(xv.z); o.w = f2bf(xv.w);
    ((ushort4*)(xbf + (size_t)t * HIDDEN))[tid] = o;
  }
  float p[NEXP];
#pragma unroll
  for (int e = 0; e < NEXP; ++e) {
    float4 gv = ((const float4*)(gw + (size_t)e * HIDDEN))[tid];
    p[e] = xv.x * gv.x + xv.y * gv.y + xv.z * gv.z + xv.w * gv.w;
  }
#pragma unroll
  for (int e = 0; e < NEXP; ++e) {
#pragma unroll
    for (int off = 32; off > 0; off >>= 1)
      p[e] += __shfl_down(p[e], off, 64);
  }
  __shared__ float red[4][NEXP];
  const int wv = tid >> 6, ln = tid & 63;
  if (ln == 0) {
#pragma unroll
    for (int e = 0; e < NEXP; ++e) red[wv][e] = p[e];
  }
  __syncthreads();
  if (tid == 0) {
    float l[NEXP];
#pragma unroll
    for (int e = 0; e < NEXP; ++e) {
      l[e] = red[0][e] + red[1][e] + red[2][e] + red[3][e];
      logits[(size_t)t * NEXP + e] = l[e];
    }
    int i0 = 0;
#pragma unroll
    for (int e = 1; e < NEXP; ++e) if (l[e] > l[i0]) i0 = e;
    int i1 = (i0 == 0) ? 1 : 0;
#pragma unroll
    for (int e = 0; e < NEXP; ++e) if (e != i0 && l[e] > l[i1]) i1 = e;
    float w0 = 1.f / (1.f + expf(l[i1] - l[i0]));
    float w1 = 1.f - w0;
    int s0 = atomicAdd(&cnt[i0], 1);
    tok[i0 * NTOK + s0] = t;  wgt[i0 * NTOK + s0] = w0;
    int s1 = atomicAdd(&cnt[i1], 1);
    tok[i1 * NTOK + s1] = t;  wgt[i1 * NTOK + s1] = w1;
  }
}

// ---------------- 64-padded per-expert row bases ----------------
__global__ void prefix_kernel(const int* __restrict__ cnt, int* __restrict__ base) {
  if (threadIdx.x == 0 && blockIdx.x == 0) {
    int b = 0;
#pragma unroll
    for (int e = 0; e < NEXP; ++e) { base[e] = b; b += ((cnt[e] + 63) >> 6) << 6; }
    base[NEXP] = b;
  }
}

// ---------------- GEMM1: H = silu(X W1^T) * (X W3^T), flatmm-style ----------------------------
// M=64 x N=64 x BK=64, 256 thr (4 waves: 2M x 2N). A (X) via g2l-staged LDS (dbuf, L2-hot);
// B (W1/W3 fp32) loaded per-lane DIRECTLY from global into registers (no LDS, no block-wide
// convoy on the HBM stream) and converted with cvt_pk. One __syncthreads/step; its vmcnt(0)
// only drains the 2 X g2l (B consumed by compute's own counted waits).
// X LDS: [64 rows][8 units of 16B]; phys unit u of row r holds global unit u^(r&7).
__global__ __launch_bounds__(256, 3) void gemm1_kernel(
    const unsigned short* __restrict__ xbf,   // [NTOK][HIDDEN] bf16
    const float* __restrict__ w1f,            // [E][FFN][HIDDEN] fp32
    const float* __restrict__ w3f,
    const int* __restrict__ cnt, const int* __restrict__ base,
    const int* __restrict__ tok,
    unsigned short* __restrict__ H)           // [MAXROWS][FFN] bf16
{
  // XCD-grouped: expert = bid%8 (one expert per XCD), mt fastest within XCD.
  const int bid  = blockIdx.x;
  const int e    = bid & 7;
  const int slot = bid >> 3;            // 0..1023
  const int mt   = slot & 31;           // 64-row token tile
  const int nt   = slot >> 5;           // 0..31, 64-col ffn tile
  const int n = cnt[e];
  if (mt * 64 >= n) return;
  const int t = threadIdx.x;
  const int w = t >> 6, l = t & 63;

  __shared__ unsigned short Xs[2][64 * 64];    // 2 x 8 KB

  // X staging: 2 g2l calls/thread; call c covers rows (w*2+c)*8 + (l>>3)
  const int lrow = (t >> 3) & 7;                       // l>>3
  const int kp   = ((t & 7) ^ lrow) << 3;              // pre-swizzled k-elem offset
  const int row0 = (w * 2    ) * 8 + lrow;
  const int row1 = (w * 2 + 1) * 8 + lrow;
  const unsigned short* xq0 = xbf + (size_t)tok[e * NTOK + min(mt * 64 + row0, n - 1)] * HIDDEN + kp;
  const unsigned short* xq1 = xbf + (size_t)tok[e * NTOK + min(mt * 64 + row1, n - 1)] * HIDDEN + kp;

  const int Moff = (w & 1) * 32;        // 2 waves over M=64
  const int Noff = (w >> 1) * 32;       // 2 waves over N=64
  const int lr = l & 15;
  const int lg = l >> 4;

  // B fragment base pointers: lane-private rows, lg folded in
  const size_t eoff = (size_t)e * FFN_DIM * HIDDEN;
  const float* b1p[2];
  const float* b3p[2];
#pragma unroll
  for (int ni = 0; ni < 2; ++ni) {
    const size_t rg = (size_t)(nt * 64 + Noff + ni * 16 + lr);
    b1p[ni] = w1f + eoff + rg * HIDDEN + lg * 8;
    b3p[ni] = w3f + eoff + rg * HIDDEN + lg * 8;
  }

  f32x4 acc1[2][2], acc3[2][2];
#pragma unroll
  for (int i = 0; i < 2; ++i)
#pragma unroll
    for (int j = 0; j < 2; ++j) { acc1[i][j] = (f32x4)0.f; acc3[i][j] = (f32x4)0.f; }

  // prologue: stage X(0)
  ld_g2l16(xq0, (char*)Xs[0] + (w * 2    ) * 1024);
  ld_g2l16(xq1, (char*)Xs[0] + (w * 2 + 1) * 1024);
  __syncthreads();

  for (int kb = 0; kb < HIDDEN / 64; ++kb) {
    const int cur = kb & 1;
    if (kb + 1 < HIDDEN / 64) {        // stage X(kb+1) into other buffer (in flight over compute)
      ld_g2l16(xq0 + (kb + 1) * 64, (char*)Xs[cur ^ 1] + (w * 2    ) * 1024);
      ld_g2l16(xq1 + (kb + 1) * 64, (char*)Xs[cur ^ 1] + (w * 2 + 1) * 1024);
    }
    // B fragments for this step: 16 float4 direct from global (per-wave counted vmcnt)
    const int ko = kb * 64;
    float4 lo[2][2][2], hi[2][2][2];   // [tensor][ni][s]
#pragma unroll
    for (int ni = 0; ni < 2; ++ni)
#pragma unroll
      for (int s = 0; s < 2; ++s) {
        lo[0][ni][s] = *(const float4*)(b1p[ni] + ko + 32 * s);
        hi[0][ni][s] = *(const float4*)(b1p[ni] + ko + 32 * s + 4);
        lo[1][ni][s] = *(const float4*)(b3p[ni] + ko + 32 * s);
        hi[1][ni][s] = *(const float4*)(b3p[ni] + ko + 32 * s + 4);
      }
    const char* Xc = (const char*)Xs[cur];
#pragma unroll
    for (int s = 0; s < 2; ++s) {
      const int ub = 4 * s + lg;
      bf16x8 a[2];
#pragma unroll
      for (int mi = 0; mi < 2; ++mi) {
        const int R = Moff + mi * 16 + lr;
        a[mi] = *(const bf16x8*)(Xc + R * 128 + ((ub ^ (R & 7)) << 4));
      }
#pragma unroll
      for (int ni = 0; ni < 2; ++ni) {
        bf16x8 b1 = cvt8b(lo[0][ni][s], hi[0][ni][s]);
        bf16x8 b3 = cvt8b(lo[1][ni][s], hi[1][ni][s]);
#pragma unroll
        for (int mi = 0; mi < 2; ++mi) {
          acc1[mi][ni] = __builtin_amdgcn_mfma_f32_16x16x32_bf16(a[mi], b1, acc1[mi][ni], 0, 0, 0);
          acc3[mi][ni] = __builtin_amdgcn_mfma_f32_16x16x32_bf16(a[mi], b3, acc3[mi][ni], 0, 0, 0);
        }
      }
    }
    __syncthreads();                   // drains only the 2 X g2l; B already consumed
  }

  const size_t rbase = (size_t)base[e] + (size_t)mt * 64;
#pragma unroll
  for (int mi = 0; mi < 2; ++mi)
#pragma unroll
    for (int ni = 0; ni < 2; ++ni)
#pragma unroll
      for (int j = 0; j < 4; ++j) {
        int row = Moff + mi * 16 + lg * 4 + j;
        int col = nt * 64 + Noff + ni * 16 + lr;
        float s1 = acc1[mi][ni][j], s3 = acc3[mi][ni][j];
        float h = (s1 / (1.f + __expf(-s1))) * s3;      // silu(s1)*s3
        H[(rbase + row) * FFN_DIM + col] = f2bf(h);
      }
}

// ---------------- GEMM2: Y = H W2^T, flatmm-style, split-K x2 ---------------------------------
__global__ __launch_bounds__(256, 4) void gemm2_kernel(
    const unsigned short* __restrict__ H,
    const float* __restrict__ w2f,            // [E][HIDDEN][FFN] fp32
    const int* __restrict__ cnt, const int* __restrict__ base,
    const int* __restrict__ tok, const float* __restrict__ wgt,
    float* __restrict__ out)
{
  const int bid  = blockIdx.x;
  const int e    = bid & 7;
  const int slot = bid >> 3;            // 0..1023
  const int mt   = slot & 31;           // 64-row token tile
  const int nt   = (slot >> 5) & 15;    // 64-col hidden tile
  const int sk   = slot >> 9;           // split-K 0..1
  const int n = cnt[e];
  if (mt * 64 >= n) return;
  const int t = threadIdx.x;
  const int w = t >> 6, l = t & 63;

  __shared__ unsigned short Hs[2][64 * 64];    // 2 x 8 KB
  __shared__ int   stok[64];
  __shared__ float swgt[64];

  if (t < 64) {
    int idx = mt * 64 + t;
    int ok = idx < n;
    stok[t] = ok ? tok[e * NTOK + idx] : -1;
    swgt[t] = ok ? wgt[e * NTOK + idx] : 0.f;
  }

  const int lrow = (t >> 3) & 7;
  const int kp   = ((t & 7) ^ lrow) << 3;
  const int row0 = (w * 2    ) * 8 + lrow;
  const int row1 = (w * 2 + 1) * 8 + lrow;
  const unsigned short* hq0 = H + (size_t)(base[e] + mt * 64 + row0) * FFN_DIM + sk * (FFN_DIM / 2) + kp;
  const unsigned short* hq1 = H + (size_t)(base[e] + mt * 64 + row1) * FFN_DIM + sk * (FFN_DIM / 2) + kp;

  const int Moff = (w & 1) * 32;
  const int Noff = (w >> 1) * 32;
  const int lr = l & 15;
  const int lg = l >> 4;

  const float* b2p[2];
#pragma unroll
  for (int ni = 0; ni < 2; ++ni) {
    const size_t rg = (size_t)(nt * 64 + Noff + ni * 16 + lr);
    b2p[ni] = w2f + (size_t)e * HIDDEN * FFN_DIM + rg * FFN_DIM + sk * (FFN_DIM / 2) + lg * 8;
  }

  f32x4 acc[2][2];
#pragma unroll
  for (int i = 0; i < 2; ++i)
#pragma unroll
    for (int j = 0; j < 2; ++j) acc[i][j] = (f32x4)0.f;

  // prologue: stage H(0)
  ld_g2l16(hq0, (char*)Hs[0] + (w * 2    ) * 1024);
  ld_g2l16(hq1, (char*)Hs[0] + (w * 2 + 1) * 1024);
  __syncthreads();

  const int NK = FFN_DIM / 2 / 64;
  for (int kb = 0; kb < NK; ++kb) {
    const int cur = kb & 1;
    if (kb + 1 < NK) {
      ld_g2l16(hq0 + (kb + 1) * 64, (char*)Hs[cur ^ 1] + (w * 2    ) * 1024);
      ld_g2l16(hq1 + (kb + 1) * 64, (char*)Hs[cur ^ 1] + (w * 2 + 1) * 1024);
    }
    const int ko = kb * 64;
    float4 lo[2][2], hi[2][2];         // [ni][s]
#pragma unroll
    for (int ni = 0; ni < 2; ++ni)
#pragma unroll
      for (int s = 0; s < 2; ++s) {
        lo[ni][s] = *(const float4*)(b2p[ni] + ko + 32 * s);
        hi[ni][s] = *(const float4*)(b2p[ni] + ko + 32 * s + 4);
      }
    const char* Hc = (const char*)Hs[cur];
#pragma unroll
    for (int s = 0; s < 2; ++s) {
      const int ub = 4 * s + lg;
      bf16x8 a[2];
#pragma unroll
      for (int mi = 0; mi < 2; ++mi) {
        const int R = Moff + mi * 16 + lr;
        a[mi] = *(const bf16x8*)(Hc + R * 128 + ((ub ^ (R & 7)) << 4));
      }
#pragma unroll
      for (int ni = 0; ni < 2; ++ni) {
        bf16x8 b = cvt8b(lo[ni][s], hi[ni][s]);
#pragma unroll
        for (int mi = 0; mi < 2; ++mi)
          acc[mi][ni] = __builtin_amdgcn_mfma_f32_16x16x32_bf16(a[mi], b, acc[mi][ni], 0, 0, 0);
      }
    }
    __syncthreads();
  }

#pragma unroll
  for (int mi = 0; mi < 2; ++mi)
#pragma unroll
    for (int ni = 0; ni < 2; ++ni)
#pragma unroll
      for (int j = 0; j < 4; ++j) {
        int row = Moff + mi * 16 + lg * 4 + j;
        int tk = stok[row];
        if (tk >= 0) {
          int col = nt * 64 + Noff + ni * 16 + lr;
          atomicAdd(&out[(size_t)tk * HIDDEN + col], swgt[row] * acc[mi][ni][j]);
        }
      }
}

// ================= fp32 fallback path (used only if ws too small) =================
#define TT 12
#define FC 256
#define NCHUNK (FFN_DIM / FC)

__global__ __launch_bounds__(256) void moe_ffn_kernel(
    const float* __restrict__ x,
    const float* __restrict__ w1, const float* __restrict__ w2,
    const float* __restrict__ w3,
    const int* __restrict__ cnt, const int* __restrict__ tok,
    const float* __restrict__ wgt, float* __restrict__ out)
{
  const int e  = blockIdx.y;
  const int n  = cnt[e];
  const int ts = blockIdx.x * TT;
  if (ts >= n) return;
  const int tid = threadIdx.x;

  __shared__ float xs[TT * HIDDEN];
  __shared__ float hc[TT * FC];
  __shared__ int   stok[TT];
  __shared__ float swgt[TT];

  if (tid < TT) {
    int idx = ts + tid;
    int tk  = (idx < n) ? tok[e * NTOK + idx] : -1;
    stok[tid] = tk;
    swgt[tid] = (idx < n) ? wgt[e * NTOK + idx] : 0.f;
  }
  __syncthreads();
#pragma unroll
  for (int i = 0; i < TT; ++i) {
    int tk = stok[i];
    float4 v = make_float4(0.f, 0.f, 0.f, 0.f);
    if (tk >= 0) v = ((const float4*)(x + (size_t)tk * HIDDEN))[tid];
    ((float4*)(xs + i * HIDDEN))[tid] = v;
  }
  __syncthreads();

  const float* w1e = w1 + (size_t)e * FFN_DIM * HIDDEN;
  const float* w3e = w3 + (size_t)e * FFN_DIM * HIDDEN;
  const float* w2e = w2 + (size_t)e * HIDDEN * FFN_DIM;

  float yacc[4][TT];
#pragma unroll
  for (int j = 0; j < 4; ++j)
#pragma unroll
    for (int t = 0; t < TT; ++t) yacc[j][t] = 0.f;

  for (int c = 0; c < NCHUNK; ++c) {
    const int f = c * FC + tid;
    const float4* r1 = (const float4*)(w1e + (size_t)f * HIDDEN);
    const float4* r3 = (const float4*)(w3e + (size_t)f * HIDDEN);
    float a1[TT], a3[TT];
#pragma unroll
    for (int t = 0; t < TT; ++t) { a1[t] = 0.f; a3[t] = 0.f; }
    for (int k = 0; k < HIDDEN / 4; ++k) {
      float4 v1 = r1[k];
      float4 v3 = r3[k];
#pragma unroll
      for (int t = 0; t < TT; ++t) {
        float4 xv = *(const float4*)(xs + t * HIDDEN + 4 * k);
        a1[t] += xv.x * v1.x + xv.y * v1.y + xv.z * v1.z + xv.w * v1.w;
        a3[t] += xv.x * v3.x + xv.y * v3.y + xv.z * v3.z + xv.w * v3.w;
      }
    }
    __syncthreads();
#pragma unroll
    for (int t = 0; t < TT; ++t) {
      float g  = a1[t];
      float sg = g / (1.f + __expf(-g));
      hc[t * FC + tid] = sg * a3[t];
    }
    __syncthreads();
    const float4* r20 = (const float4*)(w2e + (size_t)(tid      ) * FFN_DIM + c * FC);
    const float4* r21 = (const float4*)(w2e + (size_t)(tid + 256) * FFN_DIM + c * FC);
    const float4* r22 = (const float4*)(w2e + (size_t)(tid + 512) * FFN_DIM + c * FC);
    const float4* r23 = (const float4*)(w2e + (size_t)(tid + 768) * FFN_DIM + c * FC);
    for (int k = 0; k < FC / 4; ++k) {
      float4 wv0 = r20[k], wv1 = r21[k], wv2 = r22[k], wv3 = r23[k];
#pragma unroll
      for (int t = 0; t < TT; ++t) {
        float4 hv = *(const float4*)(hc + t * FC + 4 * k);
        yacc[0][t] += hv.x * wv0.x + hv.y * wv0.y + hv.z * wv0.z + hv.w * wv0.w;
        yacc[1][t] += hv.x * wv1.x + hv.y * wv1.y + hv.z * wv1.z + hv.w * wv1.w;
        yacc[2][t] += hv.x * wv2.x + hv.y * wv2.y + hv.z * wv2.z + hv.w * wv2.w;
        yacc[3][t] += hv.x * wv3.x + hv.y * wv3.y + hv.z * wv3.z + hv.w * wv3.w;
      }
    }
  }

#pragma unroll
  for (int t = 0; t < TT; ++t) {
    int tk = stok[t];
    if (tk < 0) continue;
    float wt = swgt[t];
    float* orow = out + (size_t)tk * HIDDEN;
    atomicAdd(orow + tid,       wt * yacc[0][t]);
    atomicAdd(orow + tid + 256, wt * yacc[1][t]);
    atomicAdd(orow + tid + 512, wt * yacc[2][t]);
    atomicAdd(orow + tid + 768, wt * yacc[3][t]);
  }
}

extern "C" void kernel_launch(void* const* d_in, const int* in_sizes, int n_in,
                              void* d_out, int out_size, void* d_ws, size_t ws_size,
                              hipStream_t stream) {
  const float* x  = (const float*)d_in[0];
  const float* gw = (const float*)d_in[1];
  const float* w1 = (const float*)d_in[2];
  const float* w2 = (const float*)d_in[3];
  const float* w3 = (const float*)d_in[4];
  float* out    = (float*)d_out;
  float* logits = out + (size_t)NTOK * HIDDEN;

  char* ws = (char*)d_ws;
  int*   cnt  = (int*)(ws + OFF_CNT);
  int*   base = (int*)(ws + OFF_BASE);
  int*   tokp = (int*)(ws + OFF_TOK);
  float* wgtp = (float*)(ws + OFF_WGT);

  const bool big = (ws_size >= WS_NEED);
  unsigned short* xbf  = big ? (unsigned short*)(ws + OFF_XBF) : (unsigned short*)0;
  unsigned short* Hbuf = big ? (unsigned short*)(ws + OFF_H)   : (unsigned short*)0;

  hipMemsetAsync(out, 0, (size_t)NTOK * HIDDEN * sizeof(float), stream);
  hipMemsetAsync(cnt, 0, NEXP * sizeof(int), stream);

  router_kernel<<<NTOK, 256, 0, stream>>>(x, gw, logits, cnt, tokp, wgtp, xbf);

  if (big) {
    prefix_kernel<<<1, 64, 0, stream>>>(cnt, base);
    gemm1_kernel<<<NEXP * 32 * 32, 256, 0, stream>>>(xbf, w1, w3, cnt, base, tokp, Hbuf);
    gemm2_kernel<<<NEXP * 32 * 16 * 2, 256, 0, stream>>>(Hbuf, w2, cnt, base, tokp, wgtp, out);
  } else {
    dim3 grid((NTOK + TT - 1) / TT, NEXP);
    moe_ffn_kernel<<<grid, 256, 0, stream>>>(x, w1, w2, w3, cnt, tokp, wgtp, out);
  }
}

// Round 11
// 214.494 us; speedup vs baseline: 2.8198x; 2.8198x over previous
//
#include <hip/hip_runtime.h>
#include <hip/hip_bf16.h>
#include <stdint.h>

#define HIDDEN  1024
#define FFN_DIM 2048
#define NEXP    8
#define NTOK    2048          // B*S
#define MAXROWS 5120          // sum of 64-padded per-expert counts <= 4096 + 8*63

typedef short bf16x8 __attribute__((ext_vector_type(8)));
typedef float f32x4  __attribute__((ext_vector_type(4)));

// ---------------- ws layout (bytes) ----------------
static const size_t OFF_CNT  = 0;                         // 8 ints
static const size_t OFF_BASE = 64;                        // 9 ints
static const size_t OFF_TOK  = 128;                       // 8*2048 ints
static const size_t OFF_WGT  = OFF_TOK + (size_t)NEXP*NTOK*4;
static const size_t OFF_XBF  = 131328;                    // 256-aligned
static const size_t XBF_B    = (size_t)NTOK*HIDDEN*2;
static const size_t OFF_W1S  = OFF_XBF + XBF_B;
static const size_t W_B      = (size_t)NEXP*FFN_DIM*HIDDEN*2;
static const size_t OFF_W3S  = OFF_W1S + W_B;
static const size_t OFF_W2S  = OFF_W3S + W_B;
static const size_t OFF_H    = OFF_W2S + W_B;
static const size_t H_B      = (size_t)MAXROWS*FFN_DIM*2;
static const size_t WS_NEED  = OFF_H + H_B;               // ~120 MB

__device__ __forceinline__ unsigned short f2bf(float f) {
  union { float f; unsigned u; } a; a.f = f;
  unsigned r = a.u + 0x7fff + ((a.u >> 16) & 1);          // RTN-even
  return (unsigned short)(r >> 16);
}

__device__ __forceinline__ void ld_g2l16(const void* gsrc, void* ldst) {
  __builtin_amdgcn_global_load_lds(
      (const __attribute__((address_space(1))) unsigned int*)gsrc,
      (__attribute__((address_space(3))) unsigned int*)ldst, 16, 0, 0);
}

// ---------------- Router: fp32-exact logits, top-2, renorm weights, bins; fused x->bf16 --------
__global__ __launch_bounds__(256) void router_kernel(
    const float* __restrict__ x, const float* __restrict__ gw,
    float* __restrict__ logits, int* __restrict__ cnt,
    int* __restrict__ tok, float* __restrict__ wgt,
    unsigned short* __restrict__ xbf)
{
  const int t   = blockIdx.x;
  const int tid = threadIdx.x;
  float4 xv = ((const float4*)(x + (size_t)t * HIDDEN))[tid];
  if (xbf) {
    ushort4 o;
    o.x = f2bf(xv.x); o.y = f2bf(xv.y); o.z = f2bf(xv.z); o.w = f2bf(xv.w);
    ((ushort4*)(xbf + (size_t)t * HIDDEN))[tid] = o;
  }
  float p[NEXP];
#pragma unroll
  for (int e = 0; e < NEXP; ++e) {
    float4 gv = ((const float4*)(gw + (size_t)e * HIDDEN))[tid];
    p[e] = xv.x * gv.x + xv.y * gv.y + xv.z * gv.z + xv.w * gv.w;
  }
#pragma unroll
  for (int e = 0; e < NEXP; ++e) {
#pragma unroll
    for (int off = 32; off > 0; off >>= 1)
      p[e] += __shfl_down(p[e], off, 64);
  }
  __shared__ float red[4][NEXP];
  const int wv = tid >> 6, ln = tid & 63;
  if (ln == 0) {
#pragma unroll
    for (int e = 0; e < NEXP; ++e) red[wv][e] = p[e];
  }
  __syncthreads();
  if (tid == 0) {
    float l[NEXP];
#pragma unroll
    for (int e = 0; e < NEXP; ++e) {
      l[e] = red[0][e] + red[1][e] + red[2][e] + red[3][e];
      logits[(size_t)t * NEXP + e] = l[e];
    }
    int i0 = 0;
#pragma unroll
    for (int e = 1; e < NEXP; ++e) if (l[e] > l[i0]) i0 = e;
    int i1 = (i0 == 0) ? 1 : 0;
#pragma unroll
    for (int e = 0; e < NEXP; ++e) if (e != i0 && l[e] > l[i1]) i1 = e;
    float w0 = 1.f / (1.f + expf(l[i1] - l[i0]));
    float w1 = 1.f - w0;
    int s0 = atomicAdd(&cnt[i0], 1);
    tok[i0 * NTOK + s0] = t;  wgt[i0 * NTOK + s0] = w0;
    int s1 = atomicAdd(&cnt[i1], 1);
    tok[i1 * NTOK + s1] = t;  wgt[i1 * NTOK + s1] = w1;
  }
}

// ---------------- 64-padded per-expert row bases ----------------
__global__ void prefix_kernel(const int* __restrict__ cnt, int* __restrict__ base) {
  if (threadIdx.x == 0 && blockIdx.x == 0) {
    int b = 0;
#pragma unroll
    for (int e = 0; e < NEXP; ++e) { base[e] = b; b += ((cnt[e] + 63) >> 6) << 6; }
    base[NEXP] = b;
  }
}

// ---------------- weight cvt + fragment shuffle ------------------------------------------------
// Output layout per tensor: panels of 16 rows; panel p = rows [p*16, p*16+16) of [R][C].
// Within panel: [kblk = C/32][lane=64][8 bf16], where lane holds
// W[p*16 + (lane&15)][kblk*32 + (lane>>4)*8 .. +8].  A B-fragment load in the GEMM is then
// one contiguous 1KB wave-read at (panel_base + kblk*1024B + lane*16B).
__global__ __launch_bounds__(256) void shuf_kernel(
    const float* __restrict__ w1, const float* __restrict__ w3, const float* __restrict__ w2,
    unsigned short* __restrict__ w1s, unsigned short* __restrict__ w3s,
    unsigned short* __restrict__ w2s)
{
  __shared__ unsigned short P[16 * 2048];     // 64 KB (max C)
  int bid = blockIdx.x;
  const float* src; unsigned short* dst; int C;
  if (bid < 1024)      { src = w1 + (size_t)bid * 16 * HIDDEN;  dst = w1s + (size_t)bid * 16 * HIDDEN;  C = HIDDEN; }
  else if (bid < 2048) { bid -= 1024; src = w3 + (size_t)bid * 16 * HIDDEN;  dst = w3s + (size_t)bid * 16 * HIDDEN;  C = HIDDEN; }
  else                 { bid -= 2048; src = w2 + (size_t)bid * 16 * FFN_DIM; dst = w2s + (size_t)bid * 16 * FFN_DIM; C = FFN_DIM; }
  const int t = threadIdx.x;
  const int n4 = 16 * C / 4;
  for (int i = t; i < n4; i += 256) {         // coalesced fp32 read -> bf16 LDS
    float4 v = ((const float4*)src)[i];
    ushort4 o; o.x = f2bf(v.x); o.y = f2bf(v.y); o.z = f2bf(v.z); o.w = f2bf(v.w);
    ((ushort4*)P)[i] = o;
  }
  __syncthreads();
  const int nj = 16 * C / 8;                  // #16B fragment chunks
  for (int j = t; j < nj; j += 256) {         // coalesced fragment-order write
    int kblk = j >> 6, lane = j & 63;
    int row = lane & 15, kc = kblk * 32 + (lane >> 4) * 8;
    *(uint4*)(dst + (size_t)j * 8) = *(const uint4*)(P + row * C + kc);
  }
}

// ---------------- GEMM1: H = silu(X W1^T) * (X W3^T) ------------------------------------------
// M=64 x (block N=128: 4 waves x private N=32 strip), 256 thr. X via g2l LDS (dbuf, swizzled,
// L2-hot -> cheap barrier). B fragments DIRECT from shuffled global: contiguous 1KB wave-reads,
// per-wave counted vmcnt, never block-coupled.
__global__ __launch_bounds__(256, 3) void gemm1_kernel(
    const unsigned short* __restrict__ xbf,   // [NTOK][HIDDEN] bf16
    const unsigned short* __restrict__ w1s,   // shuffled
    const unsigned short* __restrict__ w3s,
    const int* __restrict__ cnt, const int* __restrict__ base,
    const int* __restrict__ tok,
    unsigned short* __restrict__ H)           // [MAXROWS][FFN] bf16
{
  const int bid  = blockIdx.x;
  const int e    = bid & 7;                   // expert -> XCD
  const int slot = bid >> 3;                  // 0..511
  const int mt   = slot & 31;                 // 64-row token tile (mt fastest: same-nt adjacent)
  const int nt   = slot >> 5;                 // 0..15, 128-col ffn tile
  const int n = cnt[e];
  if (mt * 64 >= n) return;
  const int t = threadIdx.x;
  const int w = t >> 6, l = t & 63;

  __shared__ unsigned short Xs[2][64 * 64];   // 2 x 8 KB

  const int sr = t >> 3;                      // staged row 0..31 (and +32)
  const int kp = ((t & 7) ^ (sr & 7)) << 3;   // pre-swizzled k-elem offset
  const unsigned short* xq0 = xbf + (size_t)tok[e * NTOK + min(mt * 64 + sr, n - 1)]      * HIDDEN + kp;
  const unsigned short* xq1 = xbf + (size_t)tok[e * NTOK + min(mt * 64 + 32 + sr, n - 1)] * HIDDEN + kp;

  const int lr = l & 15;
  const int lg = l >> 4;

  // B streams: wave w owns ffn rows [nt*128 + w*32, +32) = nblks {nt*8+w*2, +1}; kblk advance 512 elems
  const size_t eoff = (size_t)e * FFN_DIM * HIDDEN;
  const unsigned short* b1p[2];
  const unsigned short* b3p[2];
#pragma unroll
  for (int ni = 0; ni < 2; ++ni) {
    const size_t nblk = (size_t)(nt * 8 + w * 2 + ni);
    b1p[ni] = w1s + eoff + nblk * (HIDDEN / 32) * 512 + l * 8;
    b3p[ni] = w3s + eoff + nblk * (HIDDEN / 32) * 512 + l * 8;
  }

  f32x4 acc1[4][2], acc3[4][2];
#pragma unroll
  for (int i = 0; i < 4; ++i)
#pragma unroll
    for (int j = 0; j < 2; ++j) { acc1[i][j] = (f32x4)0.f; acc3[i][j] = (f32x4)0.f; }

  // prologue: stage X(0)
  ld_g2l16(xq0, (char*)Xs[0] + w * 1024);
  ld_g2l16(xq1, (char*)Xs[0] + 4096 + w * 1024);
  __syncthreads();

  for (int kb = 0; kb < HIDDEN / 64; ++kb) {
    const int cur = kb & 1;
    if (kb + 1 < HIDDEN / 64) {               // stage X(kb+1), in flight across compute
      ld_g2l16(xq0 + (kb + 1) * 64, (char*)Xs[cur ^ 1] + w * 1024);
      ld_g2l16(xq1 + (kb + 1) * 64, (char*)Xs[cur ^ 1] + 4096 + w * 1024);
    }
    const char* Xc = (const char*)Xs[cur];
#pragma unroll
    for (int s = 0; s < 2; ++s) {             // 2 kblks per BK=64 step
      const int kblk = kb * 2 + s;
      bf16x8 b1[2], b3[2];
#pragma unroll
      for (int ni = 0; ni < 2; ++ni) {        // contiguous 1KB wave-reads
        b1[ni] = *(const bf16x8*)(b1p[ni] + (size_t)kblk * 512);
        b3[ni] = *(const bf16x8*)(b3p[ni] + (size_t)kblk * 512);
      }
      const int ub = 4 * s + lg;
      bf16x8 a[4];
#pragma unroll
      for (int mi = 0; mi < 4; ++mi) {
        const int R = mi * 16 + lr;
        a[mi] = *(const bf16x8*)(Xc + R * 128 + ((ub ^ (R & 7)) << 4));
      }
#pragma unroll
      for (int mi = 0; mi < 4; ++mi)
#pragma unroll
        for (int ni = 0; ni < 2; ++ni) {
          acc1[mi][ni] = __builtin_amdgcn_mfma_f32_16x16x32_bf16(a[mi], b1[ni], acc1[mi][ni], 0, 0, 0);
          acc3[mi][ni] = __builtin_amdgcn_mfma_f32_16x16x32_bf16(a[mi], b3[ni], acc3[mi][ni], 0, 0, 0);
        }
    }
    __syncthreads();                          // drains only this step's 2 X g2l
  }

  const size_t rbase = (size_t)base[e] + (size_t)mt * 64;
#pragma unroll
  for (int mi = 0; mi < 4; ++mi)
#pragma unroll
    for (int ni = 0; ni < 2; ++ni)
#pragma unroll
      for (int j = 0; j < 4; ++j) {
        int row = mi * 16 + lg * 4 + j;
        int col = nt * 128 + w * 32 + ni * 16 + lr;
        float s1 = acc1[mi][ni][j], s3 = acc3[mi][ni][j];
        float h = (s1 / (1.f + __expf(-s1))) * s3;      // silu(s1)*s3
        H[(rbase + row) * FFN_DIM + col] = f2bf(h);
      }
}

// ---------------- GEMM2: Y = H W2^T, same structure, split-K x2 --------------------------------
__global__ __launch_bounds__(256, 3) void gemm2_kernel(
    const unsigned short* __restrict__ H,
    const unsigned short* __restrict__ w2s,   // shuffled
    const int* __restrict__ cnt, const int* __restrict__ base,
    const int* __restrict__ tok, const float* __restrict__ wgt,
    float* __restrict__ out)
{
  const int bid  = blockIdx.x;
  const int e    = bid & 7;
  const int slot = bid >> 3;                  // 0..511
  const int mt   = slot & 31;                 // 64-row token tile
  const int nt   = (slot >> 5) & 7;           // 128-col hidden tile
  const int sk   = slot >> 8;                 // split-K 0..1
  const int n = cnt[e];
  if (mt * 64 >= n) return;
  const int t = threadIdx.x;
  const int w = t >> 6, l = t & 63;

  __shared__ unsigned short Hs[2][64 * 64];   // 2 x 8 KB
  __shared__ int   stok[64];
  __shared__ float swgt[64];

  if (t < 64) {
    int idx = mt * 64 + t;
    int ok = idx < n;
    stok[t] = ok ? tok[e * NTOK + idx] : -1;
    swgt[t] = ok ? wgt[e * NTOK + idx] : 0.f;
  }

  const int sr = t >> 3;
  const int kp = ((t & 7) ^ (sr & 7)) << 3;
  const unsigned short* hq0 = H + (size_t)(base[e] + mt * 64 + sr)      * FFN_DIM + sk * (FFN_DIM / 2) + kp;
  const unsigned short* hq1 = H + (size_t)(base[e] + mt * 64 + 32 + sr) * FFN_DIM + sk * (FFN_DIM / 2) + kp;

  const int lr = l & 15;
  const int lg = l >> 4;

  const unsigned short* b2p[2];
#pragma unroll
  for (int ni = 0; ni < 2; ++ni) {
    const size_t nblk = (size_t)(nt * 8 + w * 2 + ni);
    b2p[ni] = w2s + (size_t)e * HIDDEN * FFN_DIM
                  + (nblk * (FFN_DIM / 32) + (size_t)sk * 32) * 512 + l * 8;
  }

  f32x4 acc[4][2];
#pragma unroll
  for (int i = 0; i < 4; ++i)
#pragma unroll
    for (int j = 0; j < 2; ++j) acc[i][j] = (f32x4)0.f;

  ld_g2l16(hq0, (char*)Hs[0] + w * 1024);
  ld_g2l16(hq1, (char*)Hs[0] + 4096 + w * 1024);
  __syncthreads();

  const int NK = FFN_DIM / 2 / 64;            // 16 steps
  for (int kb = 0; kb < NK; ++kb) {
    const int cur = kb & 1;
    if (kb + 1 < NK) {
      ld_g2l16(hq0 + (kb + 1) * 64, (char*)Hs[cur ^ 1] + w * 1024);
      ld_g2l16(hq1 + (kb + 1) * 64, (char*)Hs[cur ^ 1] + 4096 + w * 1024);
    }
    const char* Hc = (const char*)Hs[cur];
#pragma unroll
    for (int s = 0; s < 2; ++s) {
      const int kblk = kb * 2 + s;
      bf16x8 b[2];
#pragma unroll
      for (int ni = 0; ni < 2; ++ni)
        b[ni] = *(const bf16x8*)(b2p[ni] + (size_t)kblk * 512);
      const int ub = 4 * s + lg;
      bf16x8 a[4];
#pragma unroll
      for (int mi = 0; mi < 4; ++mi) {
        const int R = mi * 16 + lr;
        a[mi] = *(const bf16x8*)(Hc + R * 128 + ((ub ^ (R & 7)) << 4));
      }
#pragma unroll
      for (int mi = 0; mi < 4; ++mi)
#pragma unroll
        for (int ni = 0; ni < 2; ++ni)
          acc[mi][ni] = __builtin_amdgcn_mfma_f32_16x16x32_bf16(a[mi], b[ni], acc[mi][ni], 0, 0, 0);
    }
    __syncthreads();
  }

#pragma unroll
  for (int mi = 0; mi < 4; ++mi)
#pragma unroll
    for (int ni = 0; ni < 2; ++ni)
#pragma unroll
      for (int j = 0; j < 4; ++j) {
        int row = mi * 16 + lg * 4 + j;
        int tk = stok[row];
        if (tk >= 0) {
          int col = nt * 128 + w * 32 + ni * 16 + lr;
          atomicAdd(&out[(size_t)tk * HIDDEN + col], swgt[row] * acc[mi][ni][j]);
        }
      }
}

// ================= fp32 fallback path (used only if ws too small) =================
#define TT 12
#define FC 256
#define NCHUNK (FFN_DIM / FC)

__global__ __launch_bounds__(256) void moe_ffn_kernel(
    const float* __restrict__ x,
    const float* __restrict__ w1, const float* __restrict__ w2,
    const float* __restrict__ w3,
    const int* __restrict__ cnt, const int* __restrict__ tok,
    const float* __restrict__ wgt, float* __restrict__ out)
{
  const int e  = blockIdx.y;
  const int n  = cnt[e];
  const int ts = blockIdx.x * TT;
  if (ts >= n) return;
  const int tid = threadIdx.x;

  __shared__ float xs[TT * HIDDEN];
  __shared__ float hc[TT * FC];
  __shared__ int   stok[TT];
  __shared__ float swgt[TT];

  if (tid < TT) {
    int idx = ts + tid;
    int tk  = (idx < n) ? tok[e * NTOK + idx] : -1;
    stok[tid] = tk;
    swgt[tid] = (idx < n) ? wgt[e * NTOK + idx] : 0.f;
  }
  __syncthreads();
#pragma unroll
  for (int i = 0; i < TT; ++i) {
    int tk = stok[i];
    float4 v = make_float4(0.f, 0.f, 0.f, 0.f);
    if (tk >= 0) v = ((const float4*)(x + (size_t)tk * HIDDEN))[tid];
    ((float4*)(xs + i * HIDDEN))[tid] = v;
  }
  __syncthreads();

  const float* w1e = w1 + (size_t)e * FFN_DIM * HIDDEN;
  const float* w3e = w3 + (size_t)e * FFN_DIM * HIDDEN;
  const float* w2e = w2 + (size_t)e * HIDDEN * FFN_DIM;

  float yacc[4][TT];
#pragma unroll
  for (int j = 0; j < 4; ++j)
#pragma unroll
    for (int t = 0; t < TT; ++t) yacc[j][t] = 0.f;

  for (int c = 0; c < NCHUNK; ++c) {
    const int f = c * FC + tid;
    const float4* r1 = (const float4*)(w1e + (size_t)f * HIDDEN);
    const float4* r3 = (const float4*)(w3e + (size_t)f * HIDDEN);
    float a1[TT], a3[TT];
#pragma unroll
    for (int t = 0; t < TT; ++t) { a1[t] = 0.f; a3[t] = 0.f; }
    for (int k = 0; k < HIDDEN / 4; ++k) {
      float4 v1 = r1[k];
      float4 v3 = r3[k];
#pragma unroll
      for (int t = 0; t < TT; ++t) {
        float4 xv = *(const float4*)(xs + t * HIDDEN + 4 * k);
        a1[t] += xv.x * v1.x + xv.y * v1.y + xv.z * v1.z + xv.w * v1.w;
        a3[t] += xv.x * v3.x + xv.y * v3.y + xv.z * v3.z + xv.w * v3.w;
      }
    }
    __syncthreads();
#pragma unroll
    for (int t = 0; t < TT; ++t) {
      float g  = a1[t];
      float sg = g / (1.f + __expf(-g));
      hc[t * FC + tid] = sg * a3[t];
    }
    __syncthreads();
    const float4* r20 = (const float4*)(w2e + (size_t)(tid      ) * FFN_DIM + c * FC);
    const float4* r21 = (const float4*)(w2e + (size_t)(tid + 256) * FFN_DIM + c * FC);
    const float4* r22 = (const float4*)(w2e + (size_t)(tid + 512) * FFN_DIM + c * FC);
    const float4* r23 = (const float4*)(w2e + (size_t)(tid + 768) * FFN_DIM + c * FC);
    for (int k = 0; k < FC / 4; ++k) {
      float4 wv0 = r20[k], wv1 = r21[k], wv2 = r22[k], wv3 = r23[k];
#pragma unroll
      for (int t = 0; t < TT; ++t) {
        float4 hv = *(const float4*)(hc + t * FC + 4 * k);
        yacc[0][t] += hv.x * wv0.x + hv.y * wv0.y + hv.z * wv0.z + hv.w * wv0.w;
        yacc[1][t] += hv.x * wv1.x + hv.y * wv1.y + hv.z * wv1.z + hv.w * wv1.w;
        yacc[2][t] += hv.x * wv2.x + hv.y * wv2.y + hv.z * wv2.z + hv.w * wv2.w;
        yacc[3][t] += hv.x * wv3.x + hv.y * wv3.y + hv.z * wv3.z + hv.w * wv3.w;
      }
    }
  }

#pragma unroll
  for (int t = 0; t < TT; ++t) {
    int tk = stok[t];
    if (tk < 0) continue;
    float wt = swgt[t];
    float* orow = out + (size_t)tk * HIDDEN;
    atomicAdd(orow + tid,       wt * yacc[0][t]);
    atomicAdd(orow + tid + 256, wt * yacc[1][t]);
    atomicAdd(orow + tid + 512, wt * yacc[2][t]);
    atomicAdd(orow + tid + 768, wt * yacc[3][t]);
  }
}

extern "C" void kernel_launch(void* const* d_in, const int* in_sizes, int n_in,
                              void* d_out, int out_size, void* d_ws, size_t ws_size,
                              hipStream_t stream) {
  const float* x  = (const float*)d_in[0];
  const float* gw = (const float*)d_in[1];
  const float* w1 = (const float*)d_in[2];
  const float* w2 = (const float*)d_in[3];
  const float* w3 = (const float*)d_in[4];
  float* out    = (float*)d_out;
  float* logits = out + (size_t)NTOK * HIDDEN;

  char* ws = (char*)d_ws;
  int*   cnt  = (int*)(ws + OFF_CNT);
  int*   base = (int*)(ws + OFF_BASE);
  int*   tokp = (int*)(ws + OFF_TOK);
  float* wgtp = (float*)(ws + OFF_WGT);

  const bool big = (ws_size >= WS_NEED);
  unsigned short* xbf  = big ? (unsigned short*)(ws + OFF_XBF) : (unsigned short*)0;
  unsigned short* w1sh = big ? (unsigned short*)(ws + OFF_W1S) : (unsigned short*)0;
  unsigned short* w3sh = big ? (unsigned short*)(ws + OFF_W3S) : (unsigned short*)0;
  unsigned short* w2sh = big ? (unsigned short*)(ws + OFF_W2S) : (unsigned short*)0;
  unsigned short* Hbuf = big ? (unsigned short*)(ws + OFF_H)   : (unsigned short*)0;

  hipMemsetAsync(out, 0, (size_t)NTOK * HIDDEN * sizeof(float), stream);
  hipMemsetAsync(cnt, 0, NEXP * sizeof(int), stream);

  router_kernel<<<NTOK, 256, 0, stream>>>(x, gw, logits, cnt, tokp, wgtp, xbf);

  if (big) {
    shuf_kernel<<<2560, 256, 0, stream>>>(w1, w3, w2, w1sh, w3sh, w2sh);
    prefix_kernel<<<1, 64, 0, stream>>>(cnt, base);

    gemm1_kernel<<<NEXP * 32 * 16, 256, 0, stream>>>(xbf, w1sh, w3sh, cnt, base, tokp, Hbuf);
    gemm2_kernel<<<NEXP * 32 * 8 * 2, 256, 0, stream>>>(Hbuf, w2sh, cnt, base, tokp, wgtp, out);
  } else {
    dim3 grid((NTOK + TT - 1) / TT, NEXP);
    moe_ffn_kernel<<<grid, 256, 0, stream>>>(x, w1, w2, w3, cnt, tokp, wgtp, out);
  }
}

// Round 12
// 209.655 us; speedup vs baseline: 2.8848x; 1.0231x over previous
//
#include <hip/hip_runtime.h>
#include <hip/hip_bf16.h>
#include <stdint.h>

#define HIDDEN  1024
#define FFN_DIM 2048
#define NEXP    8
#define NTOK    2048          // B*S
#define MAXROWS 5120          // sum of 64-padded per-expert counts <= 4096 + 8*63

typedef short bf16x8 __attribute__((ext_vector_type(8)));
typedef float f32x4  __attribute__((ext_vector_type(4)));

// ---------------- ws layout (bytes) ----------------
static const size_t OFF_CNT  = 0;                         // 8 ints
static const size_t OFF_BASE = 64;                        // 9 ints
static const size_t OFF_TOK  = 128;                       // 8*2048 ints
static const size_t OFF_WGT  = OFF_TOK + (size_t)NEXP*NTOK*4;
static const size_t OFF_XBF  = 131328;                    // 256-aligned
static const size_t XBF_B    = (size_t)NTOK*HIDDEN*2;
static const size_t OFF_W1S  = OFF_XBF + XBF_B;
static const size_t W_B      = (size_t)NEXP*FFN_DIM*HIDDEN*2;
static const size_t OFF_W3S  = OFF_W1S + W_B;
static const size_t OFF_W2S  = OFF_W3S + W_B;
static const size_t OFF_H    = OFF_W2S + W_B;
static const size_t H_B      = (size_t)MAXROWS*FFN_DIM*2;
static const size_t WS_NEED  = OFF_H + H_B;               // ~120 MB

__device__ __forceinline__ unsigned short f2bf(float f) {
  union { float f; unsigned u; } a; a.f = f;
  unsigned r = a.u + 0x7fff + ((a.u >> 16) & 1);          // RTN-even
  return (unsigned short)(r >> 16);
}

// 8 fp32 -> 8 bf16 packed into uint4 (memory order preserved)
__device__ __forceinline__ uint4 cvt8u(float4 a, float4 b) {
  uint4 r;
  asm("v_cvt_pk_bf16_f32 %0, %1, %2" : "=v"(r.x) : "v"(a.x), "v"(a.y));
  asm("v_cvt_pk_bf16_f32 %0, %1, %2" : "=v"(r.y) : "v"(a.z), "v"(a.w));
  asm("v_cvt_pk_bf16_f32 %0, %1, %2" : "=v"(r.z) : "v"(b.x), "v"(b.y));
  asm("v_cvt_pk_bf16_f32 %0, %1, %2" : "=v"(r.w) : "v"(b.z), "v"(b.w));
  return r;
}

__device__ __forceinline__ void ld_g2l16(const void* gsrc, void* ldst) {
  __builtin_amdgcn_global_load_lds(
      (const __attribute__((address_space(1))) unsigned int*)gsrc,
      (__attribute__((address_space(3))) unsigned int*)ldst, 16, 0, 0);
}

// ---------------- Router: fp32-exact logits, top-2, renorm weights, bins; fused x->bf16 --------
__global__ __launch_bounds__(256) void router_kernel(
    const float* __restrict__ x, const float* __restrict__ gw,
    float* __restrict__ logits, int* __restrict__ cnt,
    int* __restrict__ tok, float* __restrict__ wgt,
    unsigned short* __restrict__ xbf)
{
  const int t   = blockIdx.x;
  const int tid = threadIdx.x;
  float4 xv = ((const float4*)(x + (size_t)t * HIDDEN))[tid];
  if (xbf) {
    ushort4 o;
    o.x = f2bf(xv.x); o.y = f2bf(xv.y); o.z = f2bf(xv.z); o.w = f2bf(xv.w);
    ((ushort4*)(xbf + (size_t)t * HIDDEN))[tid] = o;
  }
  float p[NEXP];
#pragma unroll
  for (int e = 0; e < NEXP; ++e) {
    float4 gv = ((const float4*)(gw + (size_t)e * HIDDEN))[tid];
    p[e] = xv.x * gv.x + xv.y * gv.y + xv.z * gv.z + xv.w * gv.w;
  }
#pragma unroll
  for (int e = 0; e < NEXP; ++e) {
#pragma unroll
    for (int off = 32; off > 0; off >>= 1)
      p[e] += __shfl_down(p[e], off, 64);
  }
  __shared__ float red[4][NEXP];
  const int wv = tid >> 6, ln = tid & 63;
  if (ln == 0) {
#pragma unroll
    for (int e = 0; e < NEXP; ++e) red[wv][e] = p[e];
  }
  __syncthreads();
  if (tid == 0) {
    float l[NEXP];
#pragma unroll
    for (int e = 0; e < NEXP; ++e) {
      l[e] = red[0][e] + red[1][e] + red[2][e] + red[3][e];
      logits[(size_t)t * NEXP + e] = l[e];
    }
    int i0 = 0;
#pragma unroll
    for (int e = 1; e < NEXP; ++e) if (l[e] > l[i0]) i0 = e;
    int i1 = (i0 == 0) ? 1 : 0;
#pragma unroll
    for (int e = 0; e < NEXP; ++e) if (e != i0 && l[e] > l[i1]) i1 = e;
    float w0 = 1.f / (1.f + expf(l[i1] - l[i0]));
    float w1 = 1.f - w0;
    int s0 = atomicAdd(&cnt[i0], 1);
    tok[i0 * NTOK + s0] = t;  wgt[i0 * NTOK + s0] = w0;
    int s1 = atomicAdd(&cnt[i1], 1);
    tok[i1 * NTOK + s1] = t;  wgt[i1 * NTOK + s1] = w1;
  }
}

// ---------------- 64-padded per-expert row bases ----------------
__global__ void prefix_kernel(const int* __restrict__ cnt, int* __restrict__ base) {
  if (threadIdx.x == 0 && blockIdx.x == 0) {
    int b = 0;
#pragma unroll
    for (int e = 0; e < NEXP; ++e) { base[e] = b; b += ((cnt[e] + 63) >> 6) << 6; }
    base[NEXP] = b;
  }
}

// ---------------- weight cvt + fragment shuffle (LDS-free) -------------------------------------
// Output layout per tensor: panels of 16 rows; within panel [kblk=C/32][lane=64][8 bf16] where
// lane holds W[p*16 + (lane&15)][kblk*32 + (lane>>4)*8 .. +8].  Per output 16B chunk the thread
// reads 32B of fp32 at (row, kc); the 4 lanes sharing a row read one aligned 128B line, so a
// wave-load is exactly 16 full cache lines (same line count as contiguous) — no LDS, no
// bank conflicts, full occupancy. Write side is perfectly linear.
__global__ __launch_bounds__(256) void shuf_kernel(
    const float* __restrict__ w1, const float* __restrict__ w3, const float* __restrict__ w2,
    unsigned short* __restrict__ w1s, unsigned short* __restrict__ w3s,
    unsigned short* __restrict__ w2s)
{
  const int start  = blockIdx.x * blockDim.x + threadIdx.x;
  const int stride = gridDim.x * blockDim.x;

  // passes 0,1: C=1024 (w1,w3); pass 2: C=2048 (w2). All sizes are powers of two.
#pragma unroll
  for (int pass = 0; pass < 3; ++pass) {
    const float* s = (pass == 0) ? w1 : (pass == 1) ? w3 : w2;
    unsigned short* d = (pass == 0) ? w1s : (pass == 1) ? w3s : w2s;
    const int logC   = (pass == 2) ? 11 : 10;        // log2(C)
    const int ng     = (int)((size_t)NEXP * FFN_DIM * HIDDEN / 8);   // chunks per tensor (2M)
    for (int g = start; g < ng; g += stride) {
      const int cpp  = 1 << (logC + 1);              // chunks per panel = 2C
      const int p    = g / cpp;                      // compiler: shift (cpp is pow2 constant/2 cases)
      const int j    = g & (cpp - 1);
      const int kblk = j >> 6;
      const int lane = j & 63;
      const int row  = p * 16 + (lane & 15);
      const int kc   = kblk * 32 + ((lane >> 4) << 3);
      const float* sp = s + ((size_t)row << logC) + kc;
      float4 a = *(const float4*)(sp);
      float4 b = *(const float4*)(sp + 4);
      *(uint4*)(d + (size_t)g * 8) = cvt8u(a, b);
    }
  }
}

// ---------------- GEMM1: H = silu(X W1^T) * (X W3^T) ------------------------------------------
// M=64 x (block N=128: 4 waves x private N=32 strip), 256 thr. X via g2l LDS (dbuf, swizzled,
// L2-hot -> cheap barrier). B fragments DIRECT from shuffled global: contiguous 1KB wave-reads,
// per-wave counted vmcnt, never block-coupled.
__global__ __launch_bounds__(256, 3) void gemm1_kernel(
    const unsigned short* __restrict__ xbf,   // [NTOK][HIDDEN] bf16
    const unsigned short* __restrict__ w1s,   // shuffled
    const unsigned short* __restrict__ w3s,
    const int* __restrict__ cnt, const int* __restrict__ base,
    const int* __restrict__ tok,
    unsigned short* __restrict__ H)           // [MAXROWS][FFN] bf16
{
  const int bid  = blockIdx.x;
  const int e    = bid & 7;                   // expert -> XCD
  const int slot = bid >> 3;                  // 0..511
  const int mt   = slot & 31;                 // 64-row token tile (mt fastest: same-nt adjacent)
  const int nt   = slot >> 5;                 // 0..15, 128-col ffn tile
  const int n = cnt[e];
  if (mt * 64 >= n) return;
  const int t = threadIdx.x;
  const int w = t >> 6, l = t & 63;

  __shared__ unsigned short Xs[2][64 * 64];   // 2 x 8 KB

  const int sr = t >> 3;                      // staged row 0..31 (and +32)
  const int kp = ((t & 7) ^ (sr & 7)) << 3;   // pre-swizzled k-elem offset
  const unsigned short* xq0 = xbf + (size_t)tok[e * NTOK + min(mt * 64 + sr, n - 1)]      * HIDDEN + kp;
  const unsigned short* xq1 = xbf + (size_t)tok[e * NTOK + min(mt * 64 + 32 + sr, n - 1)] * HIDDEN + kp;

  const int lr = l & 15;
  const int lg = l >> 4;

  // B streams: wave w owns ffn rows [nt*128 + w*32, +32) = nblks {nt*8+w*2, +1}; kblk advance 512 elems
  const size_t eoff = (size_t)e * FFN_DIM * HIDDEN;
  const unsigned short* b1p[2];
  const unsigned short* b3p[2];
#pragma unroll
  for (int ni = 0; ni < 2; ++ni) {
    const size_t nblk = (size_t)(nt * 8 + w * 2 + ni);
    b1p[ni] = w1s + eoff + nblk * (HIDDEN / 32) * 512 + l * 8;
    b3p[ni] = w3s + eoff + nblk * (HIDDEN / 32) * 512 + l * 8;
  }

  f32x4 acc1[4][2], acc3[4][2];
#pragma unroll
  for (int i = 0; i < 4; ++i)
#pragma unroll
    for (int j = 0; j < 2; ++j) { acc1[i][j] = (f32x4)0.f; acc3[i][j] = (f32x4)0.f; }

  // prologue: stage X(0)
  ld_g2l16(xq0, (char*)Xs[0] + w * 1024);
  ld_g2l16(xq1, (char*)Xs[0] + 4096 + w * 1024);
  __syncthreads();

  for (int kb = 0; kb < HIDDEN / 64; ++kb) {
    const int cur = kb & 1;
    if (kb + 1 < HIDDEN / 64) {               // stage X(kb+1), in flight across compute
      ld_g2l16(xq0 + (kb + 1) * 64, (char*)Xs[cur ^ 1] + w * 1024);
      ld_g2l16(xq1 + (kb + 1) * 64, (char*)Xs[cur ^ 1] + 4096 + w * 1024);
    }
    const char* Xc = (const char*)Xs[cur];
#pragma unroll
    for (int s = 0; s < 2; ++s) {             // 2 kblks per BK=64 step
      const int kblk = kb * 2 + s;
      bf16x8 b1[2], b3[2];
#pragma unroll
      for (int ni = 0; ni < 2; ++ni) {        // contiguous 1KB wave-reads
        b1[ni] = *(const bf16x8*)(b1p[ni] + (size_t)kblk * 512);
        b3[ni] = *(const bf16x8*)(b3p[ni] + (size_t)kblk * 512);
      }
      const int ub = 4 * s + lg;
      bf16x8 a[4];
#pragma unroll
      for (int mi = 0; mi < 4; ++mi) {
        const int R = mi * 16 + lr;
        a[mi] = *(const bf16x8*)(Xc + R * 128 + ((ub ^ (R & 7)) << 4));
      }
#pragma unroll
      for (int mi = 0; mi < 4; ++mi)
#pragma unroll
        for (int ni = 0; ni < 2; ++ni) {
          acc1[mi][ni] = __builtin_amdgcn_mfma_f32_16x16x32_bf16(a[mi], b1[ni], acc1[mi][ni], 0, 0, 0);
          acc3[mi][ni] = __builtin_amdgcn_mfma_f32_16x16x32_bf16(a[mi], b3[ni], acc3[mi][ni], 0, 0, 0);
        }
    }
    __syncthreads();                          // drains only this step's 2 X g2l
  }

  const size_t rbase = (size_t)base[e] + (size_t)mt * 64;
#pragma unroll
  for (int mi = 0; mi < 4; ++mi)
#pragma unroll
    for (int ni = 0; ni < 2; ++ni)
#pragma unroll
      for (int j = 0; j < 4; ++j) {
        int row = mi * 16 + lg * 4 + j;
        int col = nt * 128 + w * 32 + ni * 16 + lr;
        float s1 = acc1[mi][ni][j], s3 = acc3[mi][ni][j];
        float h = (s1 / (1.f + __expf(-s1))) * s3;      // silu(s1)*s3
        H[(rbase + row) * FFN_DIM + col] = f2bf(h);
      }
}

// ---------------- GEMM2: Y = H W2^T, same structure, split-K x2 --------------------------------
__global__ __launch_bounds__(256, 3) void gemm2_kernel(
    const unsigned short* __restrict__ H,
    const unsigned short* __restrict__ w2s,   // shuffled
    const int* __restrict__ cnt, const int* __restrict__ base,
    const int* __restrict__ tok, const float* __restrict__ wgt,
    float* __restrict__ out)
{
  const int bid  = blockIdx.x;
  const int e    = bid & 7;
  const int slot = bid >> 3;                  // 0..511
  const int mt   = slot & 31;                 // 64-row token tile
  const int nt   = (slot >> 5) & 7;           // 128-col hidden tile
  const int sk   = slot >> 8;                 // split-K 0..1
  const int n = cnt[e];
  if (mt * 64 >= n) return;
  const int t = threadIdx.x;
  const int w = t >> 6, l = t & 63;

  __shared__ unsigned short Hs[2][64 * 64];   // 2 x 8 KB
  __shared__ int   stok[64];
  __shared__ float swgt[64];

  if (t < 64) {
    int idx = mt * 64 + t;
    int ok = idx < n;
    stok[t] = ok ? tok[e * NTOK + idx] : -1;
    swgt[t] = ok ? wgt[e * NTOK + idx] : 0.f;
  }

  const int sr = t >> 3;
  const int kp = ((t & 7) ^ (sr & 7)) << 3;
  const unsigned short* hq0 = H + (size_t)(base[e] + mt * 64 + sr)      * FFN_DIM + sk * (FFN_DIM / 2) + kp;
  const unsigned short* hq1 = H + (size_t)(base[e] + mt * 64 + 32 + sr) * FFN_DIM + sk * (FFN_DIM / 2) + kp;

  const int lr = l & 15;
  const int lg = l >> 4;

  const unsigned short* b2p[2];
#pragma unroll
  for (int ni = 0; ni < 2; ++ni) {
    const size_t nblk = (size_t)(nt * 8 + w * 2 + ni);
    b2p[ni] = w2s + (size_t)e * HIDDEN * FFN_DIM
                  + (nblk * (FFN_DIM / 32) + (size_t)sk * 32) * 512 + l * 8;
  }

  f32x4 acc[4][2];
#pragma unroll
  for (int i = 0; i < 4; ++i)
#pragma unroll
    for (int j = 0; j < 2; ++j) acc[i][j] = (f32x4)0.f;

  ld_g2l16(hq0, (char*)Hs[0] + w * 1024);
  ld_g2l16(hq1, (char*)Hs[0] + 4096 + w * 1024);
  __syncthreads();

  const int NK = FFN_DIM / 2 / 64;            // 16 steps
  for (int kb = 0; kb < NK; ++kb) {
    const int cur = kb & 1;
    if (kb + 1 < NK) {
      ld_g2l16(hq0 + (kb + 1) * 64, (char*)Hs[cur ^ 1] + w * 1024);
      ld_g2l16(hq1 + (kb + 1) * 64, (char*)Hs[cur ^ 1] + 4096 + w * 1024);
    }
    const char* Hc = (const char*)Hs[cur];
#pragma unroll
    for (int s = 0; s < 2; ++s) {
      const int kblk = kb * 2 + s;
      bf16x8 b[2];
#pragma unroll
      for (int ni = 0; ni < 2; ++ni)
        b[ni] = *(const bf16x8*)(b2p[ni] + (size_t)kblk * 512);
      const int ub = 4 * s + lg;
      bf16x8 a[4];
#pragma unroll
      for (int mi = 0; mi < 4; ++mi) {
        const int R = mi * 16 + lr;
        a[mi] = *(const bf16x8*)(Hc + R * 128 + ((ub ^ (R & 7)) << 4));
      }
#pragma unroll
      for (int mi = 0; mi < 4; ++mi)
#pragma unroll
        for (int ni = 0; ni < 2; ++ni)
          acc[mi][ni] = __builtin_amdgcn_mfma_f32_16x16x32_bf16(a[mi], b[ni], acc[mi][ni], 0, 0, 0);
    }
    __syncthreads();
  }

#pragma unroll
  for (int mi = 0; mi < 4; ++mi)
#pragma unroll
    for (int ni = 0; ni < 2; ++ni)
#pragma unroll
      for (int j = 0; j < 4; ++j) {
        int row = mi * 16 + lg * 4 + j;
        int tk = stok[row];
        if (tk >= 0) {
          int col = nt * 128 + w * 32 + ni * 16 + lr;
          atomicAdd(&out[(size_t)tk * HIDDEN + col], swgt[row] * acc[mi][ni][j]);
        }
      }
}

// ================= fp32 fallback path (used only if ws too small) =================
#define TT 12
#define FC 256
#define NCHUNK (FFN_DIM / FC)

__global__ __launch_bounds__(256) void moe_ffn_kernel(
    const float* __restrict__ x,
    const float* __restrict__ w1, const float* __restrict__ w2,
    const float* __restrict__ w3,
    const int* __restrict__ cnt, const int* __restrict__ tok,
    const float* __restrict__ wgt, float* __restrict__ out)
{
  const int e  = blockIdx.y;
  const int n  = cnt[e];
  const int ts = blockIdx.x * TT;
  if (ts >= n) return;
  const int tid = threadIdx.x;

  __shared__ float xs[TT * HIDDEN];
  __shared__ float hc[TT * FC];
  __shared__ int   stok[TT];
  __shared__ float swgt[TT];

  if (tid < TT) {
    int idx = ts + tid;
    int tk  = (idx < n) ? tok[e * NTOK + idx] : -1;
    stok[tid] = tk;
    swgt[tid] = (idx < n) ? wgt[e * NTOK + idx] : 0.f;
  }
  __syncthreads();
#pragma unroll
  for (int i = 0; i < TT; ++i) {
    int tk = stok[i];
    float4 v = make_float4(0.f, 0.f, 0.f, 0.f);
    if (tk >= 0) v = ((const float4*)(x + (size_t)tk * HIDDEN))[tid];
    ((float4*)(xs + i * HIDDEN))[tid] = v;
  }
  __syncthreads();

  const float* w1e = w1 + (size_t)e * FFN_DIM * HIDDEN;
  const float* w3e = w3 + (size_t)e * FFN_DIM * HIDDEN;
  const float* w2e = w2 + (size_t)e * HIDDEN * FFN_DIM;

  float yacc[4][TT];
#pragma unroll
  for (int j = 0; j < 4; ++j)
#pragma unroll
    for (int t = 0; t < TT; ++t) yacc[j][t] = 0.f;

  for (int c = 0; c < NCHUNK; ++c) {
    const int f = c * FC + tid;
    const float4* r1 = (const float4*)(w1e + (size_t)f * HIDDEN);
    const float4* r3 = (const float4*)(w3e + (size_t)f * HIDDEN);
    float a1[TT], a3[TT];
#pragma unroll
    for (int t = 0; t < TT; ++t) { a1[t] = 0.f; a3[t] = 0.f; }
    for (int k = 0; k < HIDDEN / 4; ++k) {
      float4 v1 = r1[k];
      float4 v3 = r3[k];
#pragma unroll
      for (int t = 0; t < TT; ++t) {
        float4 xv = *(const float4*)(xs + t * HIDDEN + 4 * k);
        a1[t] += xv.x * v1.x + xv.y * v1.y + xv.z * v1.z + xv.w * v1.w;
        a3[t] += xv.x * v3.x + xv.y * v3.y + xv.z * v3.z + xv.w * v3.w;
      }
    }
    __syncthreads();
#pragma unroll
    for (int t = 0; t < TT; ++t) {
      float g  = a1[t];
      float sg = g / (1.f + __expf(-g));
      hc[t * FC + tid] = sg * a3[t];
    }
    __syncthreads();
    const float4* r20 = (const float4*)(w2e + (size_t)(tid      ) * FFN_DIM + c * FC);
    const float4* r21 = (const float4*)(w2e + (size_t)(tid + 256) * FFN_DIM + c * FC);
    const float4* r22 = (const float4*)(w2e + (size_t)(tid + 512) * FFN_DIM + c * FC);
    const float4* r23 = (const float4*)(w2e + (size_t)(tid + 768) * FFN_DIM + c * FC);
    for (int k = 0; k < FC / 4; ++k) {
      float4 wv0 = r20[k], wv1 = r21[k], wv2 = r22[k], wv3 = r23[k];
#pragma unroll
      for (int t = 0; t < TT; ++t) {
        float4 hv = *(const float4*)(hc + t * FC + 4 * k);
        yacc[0][t] += hv.x * wv0.x + hv.y * wv0.y + hv.z * wv0.z + hv.w * wv0.w;
        yacc[1][t] += hv.x * wv1.x + hv.y * wv1.y + hv.z * wv1.z + hv.w * wv1.w;
        yacc[2][t] += hv.x * wv2.x + hv.y * wv2.y + hv.z * wv2.z + hv.w * wv2.w;
        yacc[3][t] += hv.x * wv3.x + hv.y * wv3.y + hv.z * wv3.z + hv.w * wv3.w;
      }
    }
  }

#pragma unroll
  for (int t = 0; t < TT; ++t) {
    int tk = stok[t];
    if (tk < 0) continue;
    float wt = swgt[t];
    float* orow = out + (size_t)tk * HIDDEN;
    atomicAdd(orow + tid,       wt * yacc[0][t]);
    atomicAdd(orow + tid + 256, wt * yacc[1][t]);
    atomicAdd(orow + tid + 512, wt * yacc[2][t]);
    atomicAdd(orow + tid + 768, wt * yacc[3][t]);
  }
}

extern "C" void kernel_launch(void* const* d_in, const int* in_sizes, int n_in,
                              void* d_out, int out_size, void* d_ws, size_t ws_size,
                              hipStream_t stream) {
  const float* x  = (const float*)d_in[0];
  const float* gw = (const float*)d_in[1];
  const float* w1 = (const float*)d_in[2];
  const float* w2 = (const float*)d_in[3];
  const float* w3 = (const float*)d_in[4];
  float* out    = (float*)d_out;
  float* logits = out + (size_t)NTOK * HIDDEN;

  char* ws = (char*)d_ws;
  int*   cnt  = (int*)(ws + OFF_CNT);
  int*   base = (int*)(ws + OFF_BASE);
  int*   tokp = (int*)(ws + OFF_TOK);
  float* wgtp = (float*)(ws + OFF_WGT);

  const bool big = (ws_size >= WS_NEED);
  unsigned short* xbf  = big ? (unsigned short*)(ws + OFF_XBF) : (unsigned short*)0;
  unsigned short* w1sh = big ? (unsigned short*)(ws + OFF_W1S) : (unsigned short*)0;
  unsigned short* w3sh = big ? (unsigned short*)(ws + OFF_W3S) : (unsigned short*)0;
  unsigned short* w2sh = big ? (unsigned short*)(ws + OFF_W2S) : (unsigned short*)0;
  unsigned short* Hbuf = big ? (unsigned short*)(ws + OFF_H)   : (unsigned short*)0;

  hipMemsetAsync(out, 0, (size_t)NTOK * HIDDEN * sizeof(float), stream);
  hipMemsetAsync(cnt, 0, NEXP * sizeof(int), stream);

  router_kernel<<<NTOK, 256, 0, stream>>>(x, gw, logits, cnt, tokp, wgtp, xbf);

  if (big) {
    shuf_kernel<<<2048, 256, 0, stream>>>(w1, w3, w2, w1sh, w3sh, w2sh);
    prefix_kernel<<<1, 64, 0, stream>>>(cnt, base);

    gemm1_kernel<<<NEXP * 32 * 16, 256, 0, stream>>>(xbf, w1sh, w3sh, cnt, base, tokp, Hbuf);
    gemm2_kernel<<<NEXP * 32 * 8 * 2, 256, 0, stream>>>(Hbuf, w2sh, cnt, base, tokp, wgtp, out);
  } else {
    dim3 grid((NTOK + TT - 1) / TT, NEXP);
    moe_ffn_kernel<<<grid, 256, 0, stream>>>(x, w1, w2, w3, cnt, tokp, wgtp, out);
  }
}

// Round 14
// 208.921 us; speedup vs baseline: 2.8950x; 1.0035x over previous
//
#include <hip/hip_runtime.h>
#include <hip/hip_bf16.h>
#include <stdint.h>

#define HIDDEN  1024
#define FFN_DIM 2048
#define NEXP    8
#define NTOK    2048          // B*S
#define MAXROWS 5120          // sum of 64-padded per-expert counts <= 4096 + 8*63

typedef short bf16x8 __attribute__((ext_vector_type(8)));
typedef float f32x4  __attribute__((ext_vector_type(4)));

// ---------------- ws layout (bytes) ----------------
static const size_t OFF_CNT  = 0;                         // 8 ints
static const size_t OFF_BASE = 64;                        // 9 ints
static const size_t OFF_TOK  = 128;                       // 8*2048 ints
static const size_t OFF_WGT  = OFF_TOK + (size_t)NEXP*NTOK*4;
static const size_t OFF_XBF  = 131328;                    // 256-aligned
static const size_t XBF_B    = (size_t)NTOK*HIDDEN*2;
static const size_t OFF_W1S  = OFF_XBF + XBF_B;
static const size_t W_B      = (size_t)NEXP*FFN_DIM*HIDDEN*2;
static const size_t OFF_W3S  = OFF_W1S + W_B;
static const size_t OFF_W2S  = OFF_W3S + W_B;
static const size_t OFF_H    = OFF_W2S + W_B;
static const size_t H_B      = (size_t)MAXROWS*FFN_DIM*2;
static const size_t WS_NEED  = OFF_H + H_B;               // ~120 MB

__device__ __forceinline__ unsigned short f2bf(float f) {
  union { float f; unsigned u; } a; a.f = f;
  unsigned r = a.u + 0x7fff + ((a.u >> 16) & 1);          // RTN-even
  return (unsigned short)(r >> 16);
}

__device__ __forceinline__ void ld_g2l16(const void* gsrc, void* ldst) {
  __builtin_amdgcn_global_load_lds(
      (const __attribute__((address_space(1))) unsigned int*)gsrc,
      (__attribute__((address_space(3))) unsigned int*)ldst, 16, 0, 0);
}

// ---------------- Router: fp32-exact logits, top-2, renorm weights, bins; fused x->bf16 --------
__global__ __launch_bounds__(256) void router_kernel(
    const float* __restrict__ x, const float* __restrict__ gw,
    float* __restrict__ logits, int* __restrict__ cnt,
    int* __restrict__ tok, float* __restrict__ wgt,
    unsigned short* __restrict__ xbf)
{
  const int t   = blockIdx.x;
  const int tid = threadIdx.x;
  float4 xv = ((const float4*)(x + (size_t)t * HIDDEN))[tid];
  if (xbf) {
    ushort4 o;
    o.x = f2bf(xv.x); o.y = f2bf(xv.y); o.z = f2bf(xv.z); o.w = f2bf(xv.w);
    ((ushort4*)(xbf + (size_t)t * HIDDEN))[tid] = o;
  }
  float p[NEXP];
#pragma unroll
  for (int e = 0; e < NEXP; ++e) {
    float4 gv = ((const float4*)(gw + (size_t)e * HIDDEN))[tid];
    p[e] = xv.x * gv.x + xv.y * gv.y + xv.z * gv.z + xv.w * gv.w;
  }
#pragma unroll
  for (int e = 0; e < NEXP; ++e) {
#pragma unroll
    for (int off = 32; off > 0; off >>= 1)
      p[e] += __shfl_down(p[e], off, 64);
  }
  __shared__ float red[4][NEXP];
  const int wv = tid >> 6, ln = tid & 63;
  if (ln == 0) {
#pragma unroll
    for (int e = 0; e < NEXP; ++e) red[wv][e] = p[e];
  }
  __syncthreads();
  if (tid == 0) {
    float l[NEXP];
#pragma unroll
    for (int e = 0; e < NEXP; ++e) {
      l[e] = red[0][e] + red[1][e] + red[2][e] + red[3][e];
      logits[(size_t)t * NEXP + e] = l[e];
    }
    int i0 = 0;
#pragma unroll
    for (int e = 1; e < NEXP; ++e) if (l[e] > l[i0]) i0 = e;
    int i1 = (i0 == 0) ? 1 : 0;
#pragma unroll
    for (int e = 0; e < NEXP; ++e) if (e != i0 && l[e] > l[i1]) i1 = e;
    float w0 = 1.f / (1.f + expf(l[i1] - l[i0]));
    float w1 = 1.f - w0;
    int s0 = atomicAdd(&cnt[i0], 1);
    tok[i0 * NTOK + s0] = t;  wgt[i0 * NTOK + s0] = w0;
    int s1 = atomicAdd(&cnt[i1], 1);
    tok[i1 * NTOK + s1] = t;  wgt[i1 * NTOK + s1] = w1;
  }
}

// ---------------- 64-padded per-expert row bases ----------------
__global__ void prefix_kernel(const int* __restrict__ cnt, int* __restrict__ base) {
  if (threadIdx.x == 0 && blockIdx.x == 0) {
    int b = 0;
#pragma unroll
    for (int e = 0; e < NEXP; ++e) { base[e] = b; b += ((cnt[e] + 63) >> 6) << 6; }
    base[NEXP] = b;
  }
}

// ---------------- weight cvt + fragment shuffle (coalesced reads, LDS-staged) ------------------
// Unit = (tensor, 16-row panel, 128-col chunk). Reads are fully coalesced fp32 (full lines);
// permute goes through a 4.3KB padded LDS tile; writes are linear 16B chunks in fragment order:
// per panel [kblk=C/32][lane=64][8 bf16], lane -> W[p*16+(lane&15)][kblk*32+(lane>>4)*8 ..+8].
#define SH_PAD 136   // bf16 row stride in LDS: 272B = 17x16 -> uint4-aligned
__global__ __launch_bounds__(256) void shuf_kernel(
    const float* __restrict__ w1, const float* __restrict__ w3, const float* __restrict__ w2,
    unsigned short* __restrict__ w1s, unsigned short* __restrict__ w3s,
    unsigned short* __restrict__ w2s)
{
  __shared__ unsigned short P[16 * SH_PAD];
  const int t = threadIdx.x;
  for (int u = blockIdx.x; u < 24576; u += gridDim.x) {
    const float* s; unsigned short* d; int C, v, logcpr;
    if (u < 8192)       { s = w1; d = w1s; C = HIDDEN;  v = u;         logcpr = 3; }
    else if (u < 16384) { s = w3; d = w3s; C = HIDDEN;  v = u - 8192;  logcpr = 3; }
    else                { s = w2; d = w2s; C = FFN_DIM; v = u - 16384; logcpr = 4; }
    const int p = v >> logcpr;
    const int c = v & ((1 << logcpr) - 1);
    const float* src = s + (size_t)p * 16 * C + c * 128;
    // load 16 rows x 128 fp32, fully coalesced (each row: 32 consecutive float4)
#pragma unroll
    for (int i = 0; i < 2; ++i) {
      int idx = t + i * 256;                 // 0..511
      int row = idx >> 5;
      int c4  = idx & 31;
      float4 vf = *(const float4*)(src + (size_t)row * C + c4 * 4);
      ushort4 o; o.x = f2bf(vf.x); o.y = f2bf(vf.y); o.z = f2bf(vf.z); o.w = f2bf(vf.w);
      *(ushort4*)(P + row * SH_PAD + c4 * 4) = o;
    }
    __syncthreads();
    // write 256 x 16B in fragment order (linear global stores)
    {
      int kl   = t >> 6;                     // local kblk 0..3
      int lane = t & 63;
      int row  = lane & 15;
      int kc   = kl * 32 + ((lane >> 4) << 3);
      uint4 val = *(const uint4*)(P + row * SH_PAD + kc);
      *(uint4*)(d + (size_t)p * 16 * C + ((size_t)(c * 4 + kl) * 64 + lane) * 8) = val;
    }
    __syncthreads();
  }
}

// ---------------- GEMM1: H = silu(X W1^T) * (X W3^T) ------------------------------------------
// M=64 x (block N=128: 4 waves x private N=32 strip), 256 thr. X via g2l LDS (dbuf, swizzled,
// L2-hot -> cheap barrier). B fragments DIRECT from shuffled global: contiguous 1KB wave-reads,
// per-wave counted vmcnt, never block-coupled.
__global__ __launch_bounds__(256, 3) void gemm1_kernel(
    const unsigned short* __restrict__ xbf,   // [NTOK][HIDDEN] bf16
    const unsigned short* __restrict__ w1s,   // shuffled
    const unsigned short* __restrict__ w3s,
    const int* __restrict__ cnt, const int* __restrict__ base,
    const int* __restrict__ tok,
    unsigned short* __restrict__ H)           // [MAXROWS][FFN] bf16
{
  const int bid  = blockIdx.x;
  const int e    = bid & 7;                   // expert -> XCD
  const int slot = bid >> 3;                  // 0..511
  const int mt   = slot & 31;                 // 64-row token tile (mt fastest: same-nt adjacent)
  const int nt   = slot >> 5;                 // 0..15, 128-col ffn tile
  const int n = cnt[e];
  if (mt * 64 >= n) return;
  const int t = threadIdx.x;
  const int w = t >> 6, l = t & 63;

  __shared__ unsigned short Xs[2][64 * 64];   // 2 x 8 KB

  const int sr = t >> 3;                      // staged row 0..31 (and +32)
  const int kp = ((t & 7) ^ (sr & 7)) << 3;   // pre-swizzled k-elem offset
  const unsigned short* xq0 = xbf + (size_t)tok[e * NTOK + min(mt * 64 + sr, n - 1)]      * HIDDEN + kp;
  const unsigned short* xq1 = xbf + (size_t)tok[e * NTOK + min(mt * 64 + 32 + sr, n - 1)] * HIDDEN + kp;

  const int lr = l & 15;
  const int lg = l >> 4;

  // B streams: wave w owns ffn rows [nt*128 + w*32, +32) = nblks {nt*8+w*2, +1}; kblk advance 512 elems
  const size_t eoff = (size_t)e * FFN_DIM * HIDDEN;
  const unsigned short* b1p[2];
  const unsigned short* b3p[2];
#pragma unroll
  for (int ni = 0; ni < 2; ++ni) {
    const size_t nblk = (size_t)(nt * 8 + w * 2 + ni);
    b1p[ni] = w1s + eoff + nblk * (HIDDEN / 32) * 512 + l * 8;
    b3p[ni] = w3s + eoff + nblk * (HIDDEN / 32) * 512 + l * 8;
  }

  f32x4 acc1[4][2], acc3[4][2];
#pragma unroll
  for (int i = 0; i < 4; ++i)
#pragma unroll
    for (int j = 0; j < 2; ++j) { acc1[i][j] = (f32x4)0.f; acc3[i][j] = (f32x4)0.f; }

  // prologue: stage X(0)
  ld_g2l16(xq0, (char*)Xs[0] + w * 1024);
  ld_g2l16(xq1, (char*)Xs[0] + 4096 + w * 1024);
  __syncthreads();

  for (int kb = 0; kb < HIDDEN / 64; ++kb) {
    const int cur = kb & 1;
    if (kb + 1 < HIDDEN / 64) {               // stage X(kb+1), in flight across compute
      ld_g2l16(xq0 + (kb + 1) * 64, (char*)Xs[cur ^ 1] + w * 1024);
      ld_g2l16(xq1 + (kb + 1) * 64, (char*)Xs[cur ^ 1] + 4096 + w * 1024);
    }
    const char* Xc = (const char*)Xs[cur];
#pragma unroll
    for (int s = 0; s < 2; ++s) {             // 2 kblks per BK=64 step
      const int kblk = kb * 2 + s;
      bf16x8 b1[2], b3[2];
#pragma unroll
      for (int ni = 0; ni < 2; ++ni) {        // contiguous 1KB wave-reads
        b1[ni] = *(const bf16x8*)(b1p[ni] + (size_t)kblk * 512);
        b3[ni] = *(const bf16x8*)(b3p[ni] + (size_t)kblk * 512);
      }
      const int ub = 4 * s + lg;
      bf16x8 a[4];
#pragma unroll
      for (int mi = 0; mi < 4; ++mi) {
        const int R = mi * 16 + lr;
        a[mi] = *(const bf16x8*)(Xc + R * 128 + ((ub ^ (R & 7)) << 4));
      }
#pragma unroll
      for (int mi = 0; mi < 4; ++mi)
#pragma unroll
        for (int ni = 0; ni < 2; ++ni) {
          acc1[mi][ni] = __builtin_amdgcn_mfma_f32_16x16x32_bf16(a[mi], b1[ni], acc1[mi][ni], 0, 0, 0);
          acc3[mi][ni] = __builtin_amdgcn_mfma_f32_16x16x32_bf16(a[mi], b3[ni], acc3[mi][ni], 0, 0, 0);
        }
    }
    __syncthreads();                          // drains only this step's 2 X g2l
  }

  const size_t rbase = (size_t)base[e] + (size_t)mt * 64;
#pragma unroll
  for (int mi = 0; mi < 4; ++mi)
#pragma unroll
    for (int ni = 0; ni < 2; ++ni)
#pragma unroll
      for (int j = 0; j < 4; ++j) {
        int row = mi * 16 + lg * 4 + j;
        int col = nt * 128 + w * 32 + ni * 16 + lr;
        float s1 = acc1[mi][ni][j], s3 = acc3[mi][ni][j];
        float h = (s1 / (1.f + __expf(-s1))) * s3;      // silu(s1)*s3
        H[(rbase + row) * FFN_DIM + col] = f2bf(h);
      }
}

// ---------------- GEMM2: Y = H W2^T, same structure, split-K x2 --------------------------------
__global__ __launch_bounds__(256, 3) void gemm2_kernel(
    const unsigned short* __restrict__ H,
    const unsigned short* __restrict__ w2s,   // shuffled
    const int* __restrict__ cnt, const int* __restrict__ base,
    const int* __restrict__ tok, const float* __restrict__ wgt,
    float* __restrict__ out)
{
  const int bid  = blockIdx.x;
  const int e    = bid & 7;
  const int slot = bid >> 3;                  // 0..511
  const int mt   = slot & 31;                 // 64-row token tile
  const int nt   = (slot >> 5) & 7;           // 128-col hidden tile
  const int sk   = slot >> 8;                 // split-K 0..1
  const int n = cnt[e];
  if (mt * 64 >= n) return;
  const int t = threadIdx.x;
  const int w = t >> 6, l = t & 63;

  __shared__ unsigned short Hs[2][64 * 64];   // 2 x 8 KB
  __shared__ int   stok[64];
  __shared__ float swgt[64];

  if (t < 64) {
    int idx = mt * 64 + t;
    int ok = idx < n;
    stok[t] = ok ? tok[e * NTOK + idx] : -1;
    swgt[t] = ok ? wgt[e * NTOK + idx] : 0.f;
  }

  const int sr = t >> 3;
  const int kp = ((t & 7) ^ (sr & 7)) << 3;
  const unsigned short* hq0 = H + (size_t)(base[e] + mt * 64 + sr)      * FFN_DIM + sk * (FFN_DIM / 2) + kp;
  const unsigned short* hq1 = H + (size_t)(base[e] + mt * 64 + 32 + sr) * FFN_DIM + sk * (FFN_DIM / 2) + kp;

  const int lr = l & 15;
  const int lg = l >> 4;

  const unsigned short* b2p[2];
#pragma unroll
  for (int ni = 0; ni < 2; ++ni) {
    const size_t nblk = (size_t)(nt * 8 + w * 2 + ni);
    b2p[ni] = w2s + (size_t)e * HIDDEN * FFN_DIM
                  + (nblk * (FFN_DIM / 32) + (size_t)sk * 32) * 512 + l * 8;
  }

  f32x4 acc[4][2];
#pragma unroll
  for (int i = 0; i < 4; ++i)
#pragma unroll
    for (int j = 0; j < 2; ++j) acc[i][j] = (f32x4)0.f;

  ld_g2l16(hq0, (char*)Hs[0] + w * 1024);
  ld_g2l16(hq1, (char*)Hs[0] + 4096 + w * 1024);
  __syncthreads();

  const int NK = FFN_DIM / 2 / 64;            // 16 steps
  for (int kb = 0; kb < NK; ++kb) {
    const int cur = kb & 1;
    if (kb + 1 < NK) {
      ld_g2l16(hq0 + (kb + 1) * 64, (char*)Hs[cur ^ 1] + w * 1024);
      ld_g2l16(hq1 + (kb + 1) * 64, (char*)Hs[cur ^ 1] + 4096 + w * 1024);
    }
    const char* Hc = (const char*)Hs[cur];
#pragma unroll
    for (int s = 0; s < 2; ++s) {
      const int kblk = kb * 2 + s;
      bf16x8 b[2];
#pragma unroll
      for (int ni = 0; ni < 2; ++ni)
        b[ni] = *(const bf16x8*)(b2p[ni] + (size_t)kblk * 512);
      const int ub = 4 * s + lg;
      bf16x8 a[4];
#pragma unroll
      for (int mi = 0; mi < 4; ++mi) {
        const int R = mi * 16 + lr;
        a[mi] = *(const bf16x8*)(Hc + R * 128 + ((ub ^ (R & 7)) << 4));
      }
#pragma unroll
      for (int mi = 0; mi < 4; ++mi)
#pragma unroll
        for (int ni = 0; ni < 2; ++ni)
          acc[mi][ni] = __builtin_amdgcn_mfma_f32_16x16x32_bf16(a[mi], b[ni], acc[mi][ni], 0, 0, 0);
    }
    __syncthreads();
  }

#pragma unroll
  for (int mi = 0; mi < 4; ++mi)
#pragma unroll
    for (int ni = 0; ni < 2; ++ni)
#pragma unroll
      for (int j = 0; j < 4; ++j) {
        int row = mi * 16 + lg * 4 + j;
        int tk = stok[row];
        if (tk >= 0) {
          int col = nt * 128 + w * 32 + ni * 16 + lr;
          atomicAdd(&out[(size_t)tk * HIDDEN + col], swgt[row] * acc[mi][ni][j]);
        }
      }
}

// ================= fp32 fallback path (used only if ws too small) =================
#define TT 12
#define FC 256
#define NCHUNK (FFN_DIM / FC)

__global__ __launch_bounds__(256) void moe_ffn_kernel(
    const float* __restrict__ x,
    const float* __restrict__ w1, const float* __restrict__ w2,
    const float* __restrict__ w3,
    const int* __restrict__ cnt, const int* __restrict__ tok,
    const float* __restrict__ wgt, float* __restrict__ out)
{
  const int e  = blockIdx.y;
  const int n  = cnt[e];
  const int ts = blockIdx.x * TT;
  if (ts >= n) return;
  const int tid = threadIdx.x;

  __shared__ float xs[TT * HIDDEN];
  __shared__ float hc[TT * FC];
  __shared__ int   stok[TT];
  __shared__ float swgt[TT];

  if (tid < TT) {
    int idx = ts + tid;
    int tk  = (idx < n) ? tok[e * NTOK + idx] : -1;
    stok[tid] = tk;
    swgt[tid] = (idx < n) ? wgt[e * NTOK + idx] : 0.f;
  }
  __syncthreads();
#pragma unroll
  for (int i = 0; i < TT; ++i) {
    int tk = stok[i];
    float4 v = make_float4(0.f, 0.f, 0.f, 0.f);
    if (tk >= 0) v = ((const float4*)(x + (size_t)tk * HIDDEN))[tid];
    ((float4*)(xs + i * HIDDEN))[tid] = v;
  }
  __syncthreads();

  const float* w1e = w1 + (size_t)e * FFN_DIM * HIDDEN;
  const float* w3e = w3 + (size_t)e * FFN_DIM * HIDDEN;
  const float* w2e = w2 + (size_t)e * HIDDEN * FFN_DIM;

  float yacc[4][TT];
#pragma unroll
  for (int j = 0; j < 4; ++j)
#pragma unroll
    for (int t = 0; t < TT; ++t) yacc[j][t] = 0.f;

  for (int c = 0; c < NCHUNK; ++c) {
    const int f = c * FC + tid;
    const float4* r1 = (const float4*)(w1e + (size_t)f * HIDDEN);
    const float4* r3 = (const float4*)(w3e + (size_t)f * HIDDEN);
    float a1[TT], a3[TT];
#pragma unroll
    for (int t = 0; t < TT; ++t) { a1[t] = 0.f; a3[t] = 0.f; }
    for (int k = 0; k < HIDDEN / 4; ++k) {
      float4 v1 = r1[k];
      float4 v3 = r3[k];
#pragma unroll
      for (int t = 0; t < TT; ++t) {
        float4 xv = *(const float4*)(xs + t * HIDDEN + 4 * k);
        a1[t] += xv.x * v1.x + xv.y * v1.y + xv.z * v1.z + xv.w * v1.w;
        a3[t] += xv.x * v3.x + xv.y * v3.y + xv.z * v3.z + xv.w * v3.w;
      }
    }
    __syncthreads();
#pragma unroll
    for (int t = 0; t < TT; ++t) {
      float g  = a1[t];
      float sg = g / (1.f + __expf(-g));
      hc[t * FC + tid] = sg * a3[t];
    }
    __syncthreads();
    const float4* r20 = (const float4*)(w2e + (size_t)(tid      ) * FFN_DIM + c * FC);
    const float4* r21 = (const float4*)(w2e + (size_t)(tid + 256) * FFN_DIM + c * FC);
    const float4* r22 = (const float4*)(w2e + (size_t)(tid + 512) * FFN_DIM + c * FC);
    const float4* r23 = (const float4*)(w2e + (size_t)(tid + 768) * FFN_DIM + c * FC);
    for (int k = 0; k < FC / 4; ++k) {
      float4 wv0 = r20[k], wv1 = r21[k], wv2 = r22[k], wv3 = r23[k];
#pragma unroll
      for (int t = 0; t < TT; ++t) {
        float4 hv = *(const float4*)(hc + t * FC + 4 * k);
        yacc[0][t] += hv.x * wv0.x + hv.y * wv0.y + hv.z * wv0.z + hv.w * wv0.w;
        yacc[1][t] += hv.x * wv1.x + hv.y * wv1.y + hv.z * wv1.z + hv.w * wv1.w;
        yacc[2][t] += hv.x * wv2.x + hv.y * wv2.y + hv.z * wv2.z + hv.w * wv2.w;
        yacc[3][t] += hv.x * wv3.x + hv.y * wv3.y + hv.z * wv3.z + hv.w * wv3.w;
      }
    }
  }

#pragma unroll
  for (int t = 0; t < TT; ++t) {
    int tk = stok[t];
    if (tk < 0) continue;
    float wt = swgt[t];
    float* orow = out + (size_t)tk * HIDDEN;
    atomicAdd(orow + tid,       wt * yacc[0][t]);
    atomicAdd(orow + tid + 256, wt * yacc[1][t]);
    atomicAdd(orow + tid + 512, wt * yacc[2][t]);
    atomicAdd(orow + tid + 768, wt * yacc[3][t]);
  }
}

extern "C" void kernel_launch(void* const* d_in, const int* in_sizes, int n_in,
                              void* d_out, int out_size, void* d_ws, size_t ws_size,
                              hipStream_t stream) {
  const float* x  = (const float*)d_in[0];
  const float* gw = (const float*)d_in[1];
  const float* w1 = (const float*)d_in[2];
  const float* w2 = (const float*)d_in[3];
  const float* w3 = (const float*)d_in[4];
  float* out    = (float*)d_out;
  float* logits = out + (size_t)NTOK * HIDDEN;

  char* ws = (char*)d_ws;
  int*   cnt  = (int*)(ws + OFF_CNT);
  int*   base = (int*)(ws + OFF_BASE);
  int*   tokp = (int*)(ws + OFF_TOK);
  float* wgtp = (float*)(ws + OFF_WGT);

  const bool big = (ws_size >= WS_NEED);
  unsigned short* xbf  = big ? (unsigned short*)(ws + OFF_XBF) : (unsigned short*)0;
  unsigned short* w1sh = big ? (unsigned short*)(ws + OFF_W1S) : (unsigned short*)0;
  unsigned short* w3sh = big ? (unsigned short*)(ws + OFF_W3S) : (unsigned short*)0;
  unsigned short* w2sh = big ? (unsigned short*)(ws + OFF_W2S) : (unsigned short*)0;
  unsigned short* Hbuf = big ? (unsigned short*)(ws + OFF_H)   : (unsigned short*)0;

  hipMemsetAsync(out, 0, (size_t)NTOK * HIDDEN * sizeof(float), stream);
  hipMemsetAsync(cnt, 0, NEXP * sizeof(int), stream);

  router_kernel<<<NTOK, 256, 0, stream>>>(x, gw, logits, cnt, tokp, wgtp, xbf);

  if (big) {
    shuf_kernel<<<4096, 256, 0, stream>>>(w1, w3, w2, w1sh, w3sh, w2sh);
    prefix_kernel<<<1, 64, 0, stream>>>(cnt, base);

    gemm1_kernel<<<NEXP * 32 * 16, 256, 0, stream>>>(xbf, w1sh, w3sh, cnt, base, tokp, Hbuf);
    gemm2_kernel<<<NEXP * 32 * 8 * 2, 256, 0, stream>>>(Hbuf, w2sh, cnt, base, tokp, wgtp, out);
  } else {
    dim3 grid((NTOK + TT - 1) / TT, NEXP);
    moe_ffn_kernel<<<grid, 256, 0, stream>>>(x, w1, w2, w3, cnt, tokp, wgtp, out);
  }
}